// Round 1
// baseline (914.265 us; speedup 1.0000x reference)
//
#include <hip/hip_runtime.h>

typedef __attribute__((ext_vector_type(8))) short short8;
typedef __attribute__((ext_vector_type(4))) float f32x4;

// ---------- helpers ----------
__device__ __forceinline__ ushort f2bf(float v) {
    unsigned u = __builtin_bit_cast(unsigned, v);
    unsigned r = (u + 0x7FFFu + ((u >> 16) & 1u)) >> 16;
    return (ushort)r;
}
__device__ __forceinline__ float lo16(unsigned p) { return __builtin_bit_cast(float, p << 16); }
__device__ __forceinline__ float hi16(unsigned p) { return __builtin_bit_cast(float, p & 0xFFFF0000u); }

__device__ __forceinline__ float fast_tanh(float x) {
    float cx = fminf(fmaxf(x, -9.f), 9.f);
    float e = __expf(2.f * cx);
    return (e - 1.f) / (e + 1.f);
}

__device__ __forceinline__ void async16(const void* g, void* l) {
    __builtin_amdgcn_global_load_lds(
        (const __attribute__((address_space(1))) unsigned*)g,
        (__attribute__((address_space(3))) unsigned*)l, 16, 0, 0);
}

// ---------- degree / CSR build ----------
__global__ void count_deg(const int* __restrict__ src, const int* __restrict__ dst,
                          int* outc, int* inc, int E) {
    int e = blockIdx.x * 256 + threadIdx.x;
    if (e >= E) return;
    atomicAdd(&outc[src[e]], 1);
    atomicAdd(&inc[dst[e]], 1);
}

__global__ void scan1(const int* __restrict__ cnt, int* __restrict__ part,
                      int* __restrict__ bsum, int N) {
    __shared__ int s[1024];
    int t = threadIdx.x;
    int i = blockIdx.x * 1024 + t;
    int v = (i < N) ? cnt[i] : 0;
    s[t] = v; __syncthreads();
    for (int o2 = 1; o2 < 1024; o2 <<= 1) {
        int y = (t >= o2) ? s[t - o2] : 0;
        __syncthreads();
        s[t] += y;
        __syncthreads();
    }
    if (i < N) part[i] = s[t] - v;          // exclusive within block
    if (t == 1023) bsum[blockIdx.x] = s[t]; // block total
}

__global__ void scan2(const int* __restrict__ bsum, int* __restrict__ bbase, int NB) {
    __shared__ int s[128];
    int t = threadIdx.x;
    int v = (t < NB) ? bsum[t] : 0;
    s[t] = v; __syncthreads();
    for (int o2 = 1; o2 < 128; o2 <<= 1) {
        int y = (t >= o2) ? s[t - o2] : 0;
        __syncthreads();
        s[t] += y;
        __syncthreads();
    }
    if (t < NB) bbase[t] = s[t] - v;
}

__global__ void finalize_k(int* __restrict__ roff, const int* __restrict__ bbase,
                           int* __restrict__ cursor, const int* __restrict__ outc,
                           const int* __restrict__ inc, float* __restrict__ sOut,
                           float* __restrict__ sIn, int N, int E) {
    int i = blockIdx.x * 256 + threadIdx.x;
    if (i >= N) return;
    int o = roff[i] + bbase[i >> 10];
    roff[i] = o;
    cursor[i] = o;
    int oc = outc[i]; if (oc < 1) oc = 1;
    int ic = inc[i];  if (ic < 1) ic = 1;
    sOut[i] = rsqrtf((float)oc);
    sIn[i]  = rsqrtf((float)ic);
    if (i == 0) roff[N] = E;
}

__global__ void fill_csr(const int* __restrict__ src, const int* __restrict__ dst,
                         int* __restrict__ cursor, int* __restrict__ csr, int E) {
    int e = blockIdx.x * 256 + threadIdx.x;
    if (e >= E) return;
    int p = atomicAdd(&cursor[dst[e]], 1);
    csr[p] = src[e];
}

// ---------- weight convert + transpose (fp32 KxN -> bf16 NxK), all 6 fused ----------
__global__ void convw(const float* w0, const float* w1, const float* w2,
                      const float* w3, const float* w4, const float* w5,
                      ushort* __restrict__ Wt) {
    int i = blockIdx.x * 256 + threadIdx.x; // < 262144
    int base, Km, Nm; const float* W;
    if      (i < 32768)  { base = 0;      Km = 128; Nm = 256; W = w0; }
    else if (i < 98304)  { base = 32768;  Km = 256; Nm = 256; W = w1; }
    else if (i < 131072) { base = 98304;  Km = 256; Nm = 128; W = w2; }
    else if (i < 163840) { base = 131072; Km = 128; Nm = 256; W = w3; }
    else if (i < 229376) { base = 163840; Km = 256; Nm = 256; W = w4; }
    else                 { base = 229376; Km = 256; Nm = 128; W = w5; }
    int l = i - base;
    int k = l / Nm, n = l % Nm;
    Wt[base + n * Km + k] = f2bf(W[l]);
}

// ---------- prescale in_feat * outdeg^-0.5 -> bf16 ----------
__global__ void prescale(const float* __restrict__ x, const float* __restrict__ sOut,
                         ushort* __restrict__ o, int total /* N*32 */) {
    int i = blockIdx.x * 256 + threadIdx.x;
    if (i >= total) return;
    float4 v = ((const float4*)x)[i];
    float s = sOut[i >> 5]; // 32 float4 per 128-wide row
    ushort4 r;
    r.x = f2bf(v.x * s); r.y = f2bf(v.y * s);
    r.z = f2bf(v.z * s); r.w = f2bf(v.w * s);
    ((ushort4*)o)[i] = r;
}

// ---------- aggregation kernels (one wave per dst row) ----------
__global__ __launch_bounds__(256) void agg128(const ushort* __restrict__ F,
        const int* __restrict__ csr, const int* __restrict__ roff,
        const float* __restrict__ sIn, ushort* __restrict__ out, int N) {
    int w = blockIdx.x * 4 + (threadIdx.x >> 6);
    if (w >= N) return;
    int lane = threadIdx.x & 63;
    int b = roff[w], e = roff[w + 1];
    float a0 = 0.f, a1 = 0.f;
    const ushort* base = F + lane * 2;
    int i = b;
    for (; i + 4 <= e; i += 4) {
        int s0 = csr[i], s1 = csr[i + 1], s2 = csr[i + 2], s3 = csr[i + 3];
        unsigned p0 = *(const unsigned*)(base + (size_t)s0 * 128);
        unsigned p1 = *(const unsigned*)(base + (size_t)s1 * 128);
        unsigned p2 = *(const unsigned*)(base + (size_t)s2 * 128);
        unsigned p3 = *(const unsigned*)(base + (size_t)s3 * 128);
        a0 += lo16(p0) + lo16(p1) + lo16(p2) + lo16(p3);
        a1 += hi16(p0) + hi16(p1) + hi16(p2) + hi16(p3);
    }
    for (; i < e; ++i) {
        unsigned p = *(const unsigned*)(base + (size_t)csr[i] * 128);
        a0 += lo16(p); a1 += hi16(p);
    }
    float s = sIn[w];
    ushort2 o2; o2.x = f2bf(a0 * s); o2.y = f2bf(a1 * s);
    *(ushort2*)(out + (size_t)w * 128 + lane * 2) = o2;
}

__global__ __launch_bounds__(256) void agg256(const ushort* __restrict__ F,
        const int* __restrict__ csr, const int* __restrict__ roff,
        const float* __restrict__ sIn, ushort* __restrict__ out, int N) {
    int w = blockIdx.x * 4 + (threadIdx.x >> 6);
    if (w >= N) return;
    int lane = threadIdx.x & 63;
    int b = roff[w], e = roff[w + 1];
    float a0 = 0.f, a1 = 0.f, a2 = 0.f, a3 = 0.f;
    const ushort* base = F + lane * 4;
    int i = b;
    for (; i + 4 <= e; i += 4) {
        int s0 = csr[i], s1 = csr[i + 1], s2 = csr[i + 2], s3 = csr[i + 3];
        uint2 p0 = *(const uint2*)(base + (size_t)s0 * 256);
        uint2 p1 = *(const uint2*)(base + (size_t)s1 * 256);
        uint2 p2 = *(const uint2*)(base + (size_t)s2 * 256);
        uint2 p3 = *(const uint2*)(base + (size_t)s3 * 256);
        a0 += lo16(p0.x) + lo16(p1.x) + lo16(p2.x) + lo16(p3.x);
        a1 += hi16(p0.x) + hi16(p1.x) + hi16(p2.x) + hi16(p3.x);
        a2 += lo16(p0.y) + lo16(p1.y) + lo16(p2.y) + lo16(p3.y);
        a3 += hi16(p0.y) + hi16(p1.y) + hi16(p2.y) + hi16(p3.y);
    }
    for (; i < e; ++i) {
        uint2 p = *(const uint2*)(base + (size_t)csr[i] * 256);
        a0 += lo16(p.x); a1 += hi16(p.x); a2 += lo16(p.y); a3 += hi16(p.y);
    }
    float s = sIn[w];
    ushort4 o4;
    o4.x = f2bf(a0 * s); o4.y = f2bf(a1 * s);
    o4.z = f2bf(a2 * s); o4.w = f2bf(a3 * s);
    *(ushort4*)(out + (size_t)w * 256 + lane * 4) = o4;
}

// agg (width 128) + bias + softmax; writes fp32 h to d_out and bf16 copy
__global__ __launch_bounds__(256) void agg_softmax(const ushort* __restrict__ F,
        const int* __restrict__ csr, const int* __restrict__ roff,
        const float* __restrict__ sIn, const float* __restrict__ bias,
        float* __restrict__ outh, ushort* __restrict__ outb, int N) {
    int w = blockIdx.x * 4 + (threadIdx.x >> 6);
    if (w >= N) return;
    int lane = threadIdx.x & 63;
    int b = roff[w], e = roff[w + 1];
    float a0 = 0.f, a1 = 0.f;
    const ushort* base = F + lane * 2;
    int i = b;
    for (; i + 4 <= e; i += 4) {
        int s0 = csr[i], s1 = csr[i + 1], s2 = csr[i + 2], s3 = csr[i + 3];
        unsigned p0 = *(const unsigned*)(base + (size_t)s0 * 128);
        unsigned p1 = *(const unsigned*)(base + (size_t)s1 * 128);
        unsigned p2 = *(const unsigned*)(base + (size_t)s2 * 128);
        unsigned p3 = *(const unsigned*)(base + (size_t)s3 * 128);
        a0 += lo16(p0) + lo16(p1) + lo16(p2) + lo16(p3);
        a1 += hi16(p0) + hi16(p1) + hi16(p2) + hi16(p3);
    }
    for (; i < e; ++i) {
        unsigned p = *(const unsigned*)(base + (size_t)csr[i] * 128);
        a0 += lo16(p); a1 += hi16(p);
    }
    float s = sIn[w];
    float2 bb = *(const float2*)(bias + lane * 2);
    float l0 = a0 * s + bb.x, l1 = a1 * s + bb.y;
    float m = fmaxf(l0, l1);
    for (int o = 32; o; o >>= 1) m = fmaxf(m, __shfl_xor(m, o, 64));
    float e0 = __expf(l0 - m), e1 = __expf(l1 - m);
    float sm = e0 + e1;
    for (int o = 32; o; o >>= 1) sm += __shfl_xor(sm, o, 64);
    float inv = 1.f / sm;
    float r0 = e0 * inv, r1 = e1 * inv;
    float2 fo; fo.x = r0; fo.y = r1;
    *(float2*)(outh + (size_t)w * 128 + lane * 2) = fo;
    ushort2 o2; o2.x = f2bf(r0); o2.y = f2bf(r1);
    *(ushort2*)(outb + (size_t)w * 128 + lane * 2) = o2;
}

// ---------- row softmax over 128 fp32 logits ----------
__global__ __launch_bounds__(256) void softmax_r(const float* __restrict__ L,
                                                 float* __restrict__ out, int N) {
    int w = blockIdx.x * 4 + (threadIdx.x >> 6);
    if (w >= N) return;
    int lane = threadIdx.x & 63;
    const float* row = L + (size_t)w * 128;
    float l0 = row[lane], l1 = row[lane + 64];
    float m = fmaxf(l0, l1);
    for (int o = 32; o; o >>= 1) m = fmaxf(m, __shfl_xor(m, o, 64));
    float e0 = __expf(l0 - m), e1 = __expf(l1 - m);
    float sm = e0 + e1;
    for (int o = 32; o; o >>= 1) sm += __shfl_xor(sm, o, 64);
    float inv = 1.f / sm;
    out[(size_t)w * 128 + lane] = e0 * inv;
    out[(size_t)w * 128 + 64 + lane] = e1 * inv;
}

// ---------- MFMA GEMM: A (MxK bf16) @ W (Wt: NnxK bf16, pre-transposed) ----------
// MODE 0: out = tanh(acc+bias) * (rowscale?rowscale[row]:1) -> bf16
// MODE 1: out = acc -> bf16 (no bias)
// MODE 2: out = acc + bias -> fp32
template <int MODE>
__global__ __launch_bounds__(256) void gemm_kernel(
        const ushort* __restrict__ A, const ushort* __restrict__ Wt,
        const float* __restrict__ bias, const float* __restrict__ rowscale,
        void* __restrict__ out, int M, int K, int Nn) {
    __shared__ ushort ldsA[128 * 64];
    __shared__ ushort ldsB[128 * 64];
    const int tid = threadIdx.x;
    const int lane = tid & 63;
    const int wid = tid >> 6;
    const int rowbase = blockIdx.x * 128;
    const int colbase = blockIdx.y * 128;
    const int wr = (wid >> 1) * 64;
    const int wc = (wid & 1) * 64;

    f32x4 acc[4][4];
#pragma unroll
    for (int i = 0; i < 4; ++i)
#pragma unroll
        for (int j = 0; j < 4; ++j) acc[i][j] = (f32x4){0.f, 0.f, 0.f, 0.f};

    const int sr = lane >> 3; // row within 8-row staging group
    const int sp = lane & 7;  // 16B slot within 128B row

    for (int kt = 0; kt < K; kt += 64) {
        __syncthreads();
#pragma unroll
        for (int it = 0; it < 4; ++it) {
            int rl = wid * 32 + it * 8 + sr;
            int grow = rowbase + rl; if (grow > M - 1) grow = M - 1;
            int gca = kt + ((sp ^ (rl & 7)) << 3);
            async16(A + (size_t)grow * K + gca, (char*)ldsA + (wid * 32 + it * 8) * 128);
            int gn = colbase + rl;
            int gcb = kt + ((sp ^ (rl & 7)) << 3);
            async16(Wt + (size_t)gn * K + gcb, (char*)ldsB + (wid * 32 + it * 8) * 128);
        }
        __syncthreads();
        const int l15 = lane & 15, l4 = lane >> 4;
#pragma unroll
        for (int ks = 0; ks < 2; ++ks) {
            short8 af[4], bfr[4];
#pragma unroll
            for (int rt = 0; rt < 4; ++rt) {
                int r = wr + rt * 16 + l15;
                int slot = (ks * 4 + l4) ^ (r & 7);
                af[rt] = *(const short8*)&ldsA[r * 64 + slot * 8];
            }
#pragma unroll
            for (int ct = 0; ct < 4; ++ct) {
                int n = wc + ct * 16 + l15;
                int slot = (ks * 4 + l4) ^ (n & 7);
                bfr[ct] = *(const short8*)&ldsB[n * 64 + slot * 8];
            }
#pragma unroll
            for (int rt = 0; rt < 4; ++rt)
#pragma unroll
                for (int ct = 0; ct < 4; ++ct)
                    acc[rt][ct] = __builtin_amdgcn_mfma_f32_16x16x32_bf16(
                        af[rt], bfr[ct], acc[rt][ct], 0, 0, 0);
        }
    }

    // epilogue
    const int l15 = lane & 15, l4 = lane >> 4;
    float bv[4];
#pragma unroll
    for (int ct = 0; ct < 4; ++ct)
        bv[ct] = (MODE != 1 && bias) ? bias[colbase + wc + ct * 16 + l15] : 0.f;
#pragma unroll
    for (int rt = 0; rt < 4; ++rt) {
#pragma unroll
        for (int rg = 0; rg < 4; ++rg) {
            int row = rowbase + wr + rt * 16 + l4 * 4 + rg;
            if (row >= M) continue;
            float sc = 1.f;
            if (MODE == 0 && rowscale) sc = rowscale[row];
#pragma unroll
            for (int ct = 0; ct < 4; ++ct) {
                int col = colbase + wc + ct * 16 + l15;
                float v = acc[rt][ct][rg] + bv[ct];
                if (MODE == 0) v = fast_tanh(v) * sc;
                if (MODE <= 1)
                    ((ushort*)out)[(size_t)row * Nn + col] = f2bf(v);
                else
                    ((float*)out)[(size_t)row * Nn + col] = v;
            }
        }
    }
}

// ---------- launch ----------
extern "C" void kernel_launch(void* const* d_in, const int* in_sizes, int n_in,
                              void* d_out, int out_size, void* d_ws, size_t ws_size,
                              hipStream_t stream) {
    (void)n_in; (void)out_size; (void)ws_size;
    const float* in_feat = (const float*)d_in[0];
    const int*   src     = (const int*)d_in[1];
    const int*   dstp    = (const int*)d_in[2];
    const float* Wc0 = (const float*)d_in[3];  const float* bc0 = (const float*)d_in[4];
    const float* Wc1 = (const float*)d_in[5];  const float* bc1 = (const float*)d_in[6];
    const float* Wc2 = (const float*)d_in[7];  const float* bc2 = (const float*)d_in[8];
    const float* Wr0 = (const float*)d_in[9];  const float* br0 = (const float*)d_in[10];
    const float* Wr1 = (const float*)d_in[11]; const float* br1 = (const float*)d_in[12];
    const float* Wr2 = (const float*)d_in[13]; const float* br2 = (const float*)d_in[14];

    const int N = in_sizes[0] / 128;
    const int E = in_sizes[1];

    char* ws = (char*)d_ws;
    size_t off = 0;
    auto alloc = [&](size_t bytes) -> char* {
        char* p = ws + off;
        off += (bytes + 255) & ~(size_t)255;
        return p;
    };
    char* S1 = alloc((size_t)N * 256 * 2);
    char* S2 = alloc((size_t)N * 256 * 2);
    int* csr    = (int*)alloc((size_t)E * 4);
    int* roff   = (int*)alloc((size_t)(N + 1) * 4);
    int* cursor = (int*)alloc((size_t)N * 4);
    int* outc   = (int*)alloc((size_t)N * 4);
    int* inc    = (int*)alloc((size_t)N * 4);
    float* sOut = (float*)alloc((size_t)N * 4);
    float* sIn  = (float*)alloc((size_t)N * 4);
    ushort* Wt  = (ushort*)alloc(262144 * 2);
    int* bsum   = (int*)alloc(1024);
    int* bbase  = (int*)alloc(1024);

    hipMemsetAsync(outc, 0, (size_t)N * 4, stream);
    hipMemsetAsync(inc, 0, (size_t)N * 4, stream);
    count_deg<<<(E + 255) / 256, 256, 0, stream>>>(src, dstp, outc, inc, E);
    int NB = (N + 1023) / 1024; // 98 for N=100000 (must be <=128)
    scan1<<<NB, 1024, 0, stream>>>(inc, roff, bsum, N);
    scan2<<<1, 128, 0, stream>>>(bsum, bbase, NB);
    finalize_k<<<(N + 255) / 256, 256, 0, stream>>>(roff, bbase, cursor, outc, inc, sOut, sIn, N, E);
    fill_csr<<<(E + 255) / 256, 256, 0, stream>>>(src, dstp, cursor, csr, E);
    convw<<<262144 / 256, 256, 0, stream>>>(Wc0, Wc1, Wc2, Wr0, Wr1, Wr2, Wt);

    ushort* Xs = (ushort*)S1;
    prescale<<<(N * 32 + 255) / 256, 256, 0, stream>>>(in_feat, sOut, Xs, N * 32);

    int aggGrid = (N + 3) / 4;
    dim3 g2((N + 127) / 128, 2), g1((N + 127) / 128, 1);

    ushort* A0 = (ushort*)S2;
    agg128<<<aggGrid, 256, 0, stream>>>(Xs, csr, roff, sIn, A0, N);
    ushort* B1 = (ushort*)S1;
    gemm_kernel<0><<<g2, 256, 0, stream>>>(A0, Wt, bc0, sOut, B1, N, 128, 256);
    ushort* A1 = (ushort*)S2;
    agg256<<<aggGrid, 256, 0, stream>>>(B1, csr, roff, sIn, A1, N);
    ushort* B2 = (ushort*)S1;
    gemm_kernel<0><<<g2, 256, 0, stream>>>(A1, Wt + 32768, bc1, sOut, B2, N, 256, 256);
    ushort* T3 = (ushort*)S2;
    gemm_kernel<1><<<g1, 256, 0, stream>>>(B2, Wt + 98304, nullptr, nullptr, T3, N, 256, 128);
    float* outh = (float*)d_out;
    ushort* Hbf = (ushort*)S1;
    agg_softmax<<<aggGrid, 256, 0, stream>>>(T3, csr, roff, sIn, bc2, outh, Hbf, N);
    ushort* R1 = (ushort*)S2;
    gemm_kernel<0><<<g2, 256, 0, stream>>>(Hbf, Wt + 131072, br0, nullptr, R1, N, 128, 256);
    ushort* R2 = (ushort*)S1;
    gemm_kernel<0><<<g2, 256, 0, stream>>>(R1, Wt + 163840, br1, nullptr, R2, N, 256, 256);
    float* logits = (float*)S2;
    gemm_kernel<2><<<g1, 256, 0, stream>>>(R2, Wt + 229376, br2, nullptr, logits, N, 256, 128);
    softmax_r<<<aggGrid, 256, 0, stream>>>(logits, outh + (size_t)N * 128, N);
}

// Round 2
// 766.893 us; speedup vs baseline: 1.1922x; 1.1922x over previous
//
#include <hip/hip_runtime.h>

typedef __attribute__((ext_vector_type(8))) short short8;
typedef __attribute__((ext_vector_type(4))) float f32x4;

// ---------- helpers ----------
__device__ __forceinline__ ushort f2bf(float v) {
    unsigned u = __builtin_bit_cast(unsigned, v);
    unsigned r = (u + 0x7FFFu + ((u >> 16) & 1u)) >> 16;
    return (ushort)r;
}
__device__ __forceinline__ float lo16(unsigned p) { return __builtin_bit_cast(float, p << 16); }
__device__ __forceinline__ float hi16(unsigned p) { return __builtin_bit_cast(float, p & 0xFFFF0000u); }

__device__ __forceinline__ float fast_tanh(float x) {
    float cx = fminf(fmaxf(x, -9.f), 9.f);
    float e = __expf(2.f * cx);
    return (e - 1.f) / (e + 1.f);
}

__device__ __forceinline__ void async16(const void* g, void* l) {
    __builtin_amdgcn_global_load_lds(
        (const __attribute__((address_space(1))) unsigned*)g,
        (__attribute__((address_space(3))) unsigned*)l, 16, 0, 0);
}

#define BSHIFT 9          // 512 nodes per bucket
#define CHUNK 4096        // edges per partition block

// ---------- CSR build: bucketed counting sort ----------
// Pass 1a: per-bucket histogram (LDS-reduced) + out-degree atomics
__global__ __launch_bounds__(256) void bucket_count(const int* __restrict__ src,
        const int* __restrict__ dst, int* __restrict__ gbc,
        int* __restrict__ outc, int E) {
    __shared__ int cnt[256];
    int t = threadIdx.x;
    cnt[t] = 0;
    __syncthreads();
    int start = blockIdx.x * CHUNK;
    int n = E - start; if (n > CHUNK) n = CHUNK;
#pragma unroll
    for (int k = 0; k < CHUNK / 256; ++k) {
        int i = t + k * 256;
        if (i < n) {
            atomicAdd(&cnt[dst[start + i] >> BSHIFT], 1);
            atomicAdd(&outc[src[start + i]], 1);
        }
    }
    __syncthreads();
    if (cnt[t]) atomicAdd(&gbc[t], cnt[t]);
}

// Pass 1b: scan bucket counts -> bucket bases (= csr segment bases) + cursors
__global__ void scan_buckets(const int* __restrict__ gbc, int* __restrict__ bucketBase,
                             int* __restrict__ pairCursor, int* __restrict__ roff,
                             int N, int E) {
    __shared__ int s[256];
    int t = threadIdx.x;
    int v = gbc[t];
    s[t] = v; __syncthreads();
    for (int o = 1; o < 256; o <<= 1) {
        int y = (t >= o) ? s[t - o] : 0;
        __syncthreads();
        s[t] += y;
        __syncthreads();
    }
    int excl = s[t] - v;
    bucketBase[t] = excl;
    pairCursor[t] = excl;
    if (t == 255) bucketBase[256] = s[255];
    if (t == 0) roff[N] = E;
}

// Pass 2: partition edges into bucketed pairs array (contiguous runs per bucket)
__global__ __launch_bounds__(256) void part_scatter(const int* __restrict__ src,
        const int* __restrict__ dst, int* __restrict__ pairCursor,
        uint2* __restrict__ pairs, int E) {
    __shared__ int cnt[256];
    __shared__ int base[256];
    int t = threadIdx.x;
    cnt[t] = 0;
    __syncthreads();
    int start = blockIdx.x * CHUNK;
    int n = E - start; if (n > CHUNK) n = CHUNK;
    int sv[CHUNK / 256], dv[CHUNK / 256], rk[CHUNK / 256], bk[CHUNK / 256];
#pragma unroll
    for (int k = 0; k < CHUNK / 256; ++k) {
        int i = t + k * 256;
        if (i < n) {
            sv[k] = src[start + i];
            dv[k] = dst[start + i];
            bk[k] = dv[k] >> BSHIFT;
            rk[k] = atomicAdd(&cnt[bk[k]], 1);
        } else bk[k] = -1;
    }
    __syncthreads();
    base[t] = cnt[t] ? atomicAdd(&pairCursor[t], cnt[t]) : 0;
    __syncthreads();
#pragma unroll
    for (int k = 0; k < CHUNK / 256; ++k)
        if (bk[k] >= 0) pairs[base[bk[k]] + rk[k]] = make_uint2((unsigned)sv[k], (unsigned)dv[k]);
}

// Pass 3: per-bucket node counts + scan in LDS -> roff/sIn; LDS-cursor csr scatter
__global__ __launch_bounds__(256) void build_bucket(const uint2* __restrict__ pairs,
        const int* __restrict__ bucketBase, int* __restrict__ roff,
        float* __restrict__ sIn, int* __restrict__ csr, int N) {
    __shared__ int cnt[512];
    __shared__ int cur[512];
    __shared__ int ss[256];
    int b = blockIdx.x;
    int t = threadIdx.x;
    int lo = b << BSHIFT;
    int s0 = bucketBase[b], s1 = bucketBase[b + 1];
    cnt[t] = 0; cnt[t + 256] = 0;
    __syncthreads();
    for (int j = s0 + t; j < s1; j += 256)
        atomicAdd(&cnt[pairs[j].y - lo], 1);
    __syncthreads();
    int c0 = cnt[2 * t], c1 = cnt[2 * t + 1];
    ss[t] = c0 + c1; __syncthreads();
    for (int o = 1; o < 256; o <<= 1) {
        int y = (t >= o) ? ss[t - o] : 0;
        __syncthreads();
        ss[t] += y;
        __syncthreads();
    }
    int eb = ss[t] - (c0 + c1);
    int p0 = s0 + eb, p1 = s0 + eb + c0;
    cur[2 * t] = p0; cur[2 * t + 1] = p1;
    int n0 = lo + 2 * t, n1 = n0 + 1;
    if (n0 < N) { roff[n0] = p0; sIn[n0] = rsqrtf((float)(c0 > 0 ? c0 : 1)); }
    if (n1 < N) { roff[n1] = p1; sIn[n1] = rsqrtf((float)(c1 > 0 ? c1 : 1)); }
    __syncthreads();
    for (int j = s0 + t; j < s1; j += 256) {
        uint2 p = pairs[j];
        int pos = atomicAdd(&cur[p.y - lo], 1);
        csr[pos] = (int)p.x;
    }
}

// ---------- weight convert + transpose (fp32 KxN -> bf16 NxK), all 6 fused ----------
__global__ void convw(const float* w0, const float* w1, const float* w2,
                      const float* w3, const float* w4, const float* w5,
                      ushort* __restrict__ Wt) {
    int i = blockIdx.x * 256 + threadIdx.x; // < 262144
    int base, Km, Nm; const float* W;
    if      (i < 32768)  { base = 0;      Km = 128; Nm = 256; W = w0; }
    else if (i < 98304)  { base = 32768;  Km = 256; Nm = 256; W = w1; }
    else if (i < 131072) { base = 98304;  Km = 256; Nm = 128; W = w2; }
    else if (i < 163840) { base = 131072; Km = 128; Nm = 256; W = w3; }
    else if (i < 229376) { base = 163840; Km = 256; Nm = 256; W = w4; }
    else                 { base = 229376; Km = 256; Nm = 128; W = w5; }
    int l = i - base;
    int k = l / Nm, n = l % Nm;
    Wt[base + n * Km + k] = f2bf(W[l]);
}

// ---------- prescale in_feat * outdeg^-0.5 -> bf16 (computes sOut inline) ----------
__global__ void prescale(const float* __restrict__ x, const int* __restrict__ outc,
                         ushort* __restrict__ o, float* __restrict__ sOut,
                         int total /* N*32 */) {
    int i = blockIdx.x * 256 + threadIdx.x;
    if (i >= total) return;
    int row = i >> 5; // 32 float4 per 128-wide row
    int oc = outc[row]; if (oc < 1) oc = 1;
    float s = rsqrtf((float)oc);
    if ((i & 31) == 0) sOut[row] = s;
    float4 v = ((const float4*)x)[i];
    ushort4 r;
    r.x = f2bf(v.x * s); r.y = f2bf(v.y * s);
    r.z = f2bf(v.z * s); r.w = f2bf(v.w * s);
    ((ushort4*)o)[i] = r;
}

// ---------- aggregation kernels (one wave per dst row) ----------
__global__ __launch_bounds__(256) void agg128(const ushort* __restrict__ F,
        const int* __restrict__ csr, const int* __restrict__ roff,
        const float* __restrict__ sIn, ushort* __restrict__ out, int N) {
    int w = blockIdx.x * 4 + (threadIdx.x >> 6);
    if (w >= N) return;
    int lane = threadIdx.x & 63;
    int b = roff[w], e = roff[w + 1];
    float a0 = 0.f, a1 = 0.f;
    const ushort* base = F + lane * 2;
    int i = b;
    for (; i + 4 <= e; i += 4) {
        int s0 = csr[i], s1 = csr[i + 1], s2 = csr[i + 2], s3 = csr[i + 3];
        unsigned p0 = *(const unsigned*)(base + (size_t)s0 * 128);
        unsigned p1 = *(const unsigned*)(base + (size_t)s1 * 128);
        unsigned p2 = *(const unsigned*)(base + (size_t)s2 * 128);
        unsigned p3 = *(const unsigned*)(base + (size_t)s3 * 128);
        a0 += lo16(p0) + lo16(p1) + lo16(p2) + lo16(p3);
        a1 += hi16(p0) + hi16(p1) + hi16(p2) + hi16(p3);
    }
    for (; i < e; ++i) {
        unsigned p = *(const unsigned*)(base + (size_t)csr[i] * 128);
        a0 += lo16(p); a1 += hi16(p);
    }
    float s = sIn[w];
    ushort2 o2; o2.x = f2bf(a0 * s); o2.y = f2bf(a1 * s);
    *(ushort2*)(out + (size_t)w * 128 + lane * 2) = o2;
}

__global__ __launch_bounds__(256) void agg256(const ushort* __restrict__ F,
        const int* __restrict__ csr, const int* __restrict__ roff,
        const float* __restrict__ sIn, ushort* __restrict__ out, int N) {
    int w = blockIdx.x * 4 + (threadIdx.x >> 6);
    if (w >= N) return;
    int lane = threadIdx.x & 63;
    int b = roff[w], e = roff[w + 1];
    float a0 = 0.f, a1 = 0.f, a2 = 0.f, a3 = 0.f;
    const ushort* base = F + lane * 4;
    int i = b;
    for (; i + 4 <= e; i += 4) {
        int s0 = csr[i], s1 = csr[i + 1], s2 = csr[i + 2], s3 = csr[i + 3];
        uint2 p0 = *(const uint2*)(base + (size_t)s0 * 256);
        uint2 p1 = *(const uint2*)(base + (size_t)s1 * 256);
        uint2 p2 = *(const uint2*)(base + (size_t)s2 * 256);
        uint2 p3 = *(const uint2*)(base + (size_t)s3 * 256);
        a0 += lo16(p0.x) + lo16(p1.x) + lo16(p2.x) + lo16(p3.x);
        a1 += hi16(p0.x) + hi16(p1.x) + hi16(p2.x) + hi16(p3.x);
        a2 += lo16(p0.y) + lo16(p1.y) + lo16(p2.y) + lo16(p3.y);
        a3 += hi16(p0.y) + hi16(p1.y) + hi16(p2.y) + hi16(p3.y);
    }
    for (; i < e; ++i) {
        uint2 p = *(const uint2*)(base + (size_t)csr[i] * 256);
        a0 += lo16(p.x); a1 += hi16(p.x); a2 += lo16(p.y); a3 += hi16(p.y);
    }
    float s = sIn[w];
    ushort4 o4;
    o4.x = f2bf(a0 * s); o4.y = f2bf(a1 * s);
    o4.z = f2bf(a2 * s); o4.w = f2bf(a3 * s);
    *(ushort4*)(out + (size_t)w * 256 + lane * 4) = o4;
}

// agg (width 128) + bias + softmax; writes fp32 h to d_out and bf16 copy
__global__ __launch_bounds__(256) void agg_softmax(const ushort* __restrict__ F,
        const int* __restrict__ csr, const int* __restrict__ roff,
        const float* __restrict__ sIn, const float* __restrict__ bias,
        float* __restrict__ outh, ushort* __restrict__ outb, int N) {
    int w = blockIdx.x * 4 + (threadIdx.x >> 6);
    if (w >= N) return;
    int lane = threadIdx.x & 63;
    int b = roff[w], e = roff[w + 1];
    float a0 = 0.f, a1 = 0.f;
    const ushort* base = F + lane * 2;
    int i = b;
    for (; i + 4 <= e; i += 4) {
        int s0 = csr[i], s1 = csr[i + 1], s2 = csr[i + 2], s3 = csr[i + 3];
        unsigned p0 = *(const unsigned*)(base + (size_t)s0 * 128);
        unsigned p1 = *(const unsigned*)(base + (size_t)s1 * 128);
        unsigned p2 = *(const unsigned*)(base + (size_t)s2 * 128);
        unsigned p3 = *(const unsigned*)(base + (size_t)s3 * 128);
        a0 += lo16(p0) + lo16(p1) + lo16(p2) + lo16(p3);
        a1 += hi16(p0) + hi16(p1) + hi16(p2) + hi16(p3);
    }
    for (; i < e; ++i) {
        unsigned p = *(const unsigned*)(base + (size_t)csr[i] * 128);
        a0 += lo16(p); a1 += hi16(p);
    }
    float s = sIn[w];
    float2 bb = *(const float2*)(bias + lane * 2);
    float l0 = a0 * s + bb.x, l1 = a1 * s + bb.y;
    float m = fmaxf(l0, l1);
    for (int o = 32; o; o >>= 1) m = fmaxf(m, __shfl_xor(m, o, 64));
    float e0 = __expf(l0 - m), e1 = __expf(l1 - m);
    float sm = e0 + e1;
    for (int o = 32; o; o >>= 1) sm += __shfl_xor(sm, o, 64);
    float inv = 1.f / sm;
    float r0 = e0 * inv, r1 = e1 * inv;
    float2 fo; fo.x = r0; fo.y = r1;
    *(float2*)(outh + (size_t)w * 128 + lane * 2) = fo;
    ushort2 o2; o2.x = f2bf(r0); o2.y = f2bf(r1);
    *(ushort2*)(outb + (size_t)w * 128 + lane * 2) = o2;
}

// ---------- row softmax over 128 fp32 logits ----------
__global__ __launch_bounds__(256) void softmax_r(const float* __restrict__ L,
                                                 float* __restrict__ out, int N) {
    int w = blockIdx.x * 4 + (threadIdx.x >> 6);
    if (w >= N) return;
    int lane = threadIdx.x & 63;
    const float* row = L + (size_t)w * 128;
    float l0 = row[lane], l1 = row[lane + 64];
    float m = fmaxf(l0, l1);
    for (int o = 32; o; o >>= 1) m = fmaxf(m, __shfl_xor(m, o, 64));
    float e0 = __expf(l0 - m), e1 = __expf(l1 - m);
    float sm = e0 + e1;
    for (int o = 32; o; o >>= 1) sm += __shfl_xor(sm, o, 64);
    float inv = 1.f / sm;
    out[(size_t)w * 128 + lane] = e0 * inv;
    out[(size_t)w * 128 + 64 + lane] = e1 * inv;
}

// ---------- MFMA GEMM: A (MxK bf16) @ W (Wt: NnxK bf16, pre-transposed) ----------
// MODE 0: out = tanh(acc+bias) * (rowscale?rowscale[row]:1) -> bf16
// MODE 1: out = acc -> bf16 (no bias)
// MODE 2: out = acc + bias -> fp32
template <int MODE>
__global__ __launch_bounds__(256) void gemm_kernel(
        const ushort* __restrict__ A, const ushort* __restrict__ Wt,
        const float* __restrict__ bias, const float* __restrict__ rowscale,
        void* __restrict__ out, int M, int K, int Nn) {
    __shared__ ushort ldsA[128 * 64];
    __shared__ ushort ldsB[128 * 64];
    const int tid = threadIdx.x;
    const int lane = tid & 63;
    const int wid = tid >> 6;
    const int rowbase = blockIdx.x * 128;
    const int colbase = blockIdx.y * 128;
    const int wr = (wid >> 1) * 64;
    const int wc = (wid & 1) * 64;

    f32x4 acc[4][4];
#pragma unroll
    for (int i = 0; i < 4; ++i)
#pragma unroll
        for (int j = 0; j < 4; ++j) acc[i][j] = (f32x4){0.f, 0.f, 0.f, 0.f};

    const int sr = lane >> 3; // row within 8-row staging group
    const int sp = lane & 7;  // 16B slot within 128B row

    for (int kt = 0; kt < K; kt += 64) {
        __syncthreads();
#pragma unroll
        for (int it = 0; it < 4; ++it) {
            int rl = wid * 32 + it * 8 + sr;
            int grow = rowbase + rl; if (grow > M - 1) grow = M - 1;
            int gca = kt + ((sp ^ (rl & 7)) << 3);
            async16(A + (size_t)grow * K + gca, (char*)ldsA + (wid * 32 + it * 8) * 128);
            int gn = colbase + rl;
            int gcb = kt + ((sp ^ (rl & 7)) << 3);
            async16(Wt + (size_t)gn * K + gcb, (char*)ldsB + (wid * 32 + it * 8) * 128);
        }
        __syncthreads();
        const int l15 = lane & 15, l4 = lane >> 4;
#pragma unroll
        for (int ks = 0; ks < 2; ++ks) {
            short8 af[4], bfr[4];
#pragma unroll
            for (int rt = 0; rt < 4; ++rt) {
                int r = wr + rt * 16 + l15;
                int slot = (ks * 4 + l4) ^ (r & 7);
                af[rt] = *(const short8*)&ldsA[r * 64 + slot * 8];
            }
#pragma unroll
            for (int ct = 0; ct < 4; ++ct) {
                int n = wc + ct * 16 + l15;
                int slot = (ks * 4 + l4) ^ (n & 7);
                bfr[ct] = *(const short8*)&ldsB[n * 64 + slot * 8];
            }
#pragma unroll
            for (int rt = 0; rt < 4; ++rt)
#pragma unroll
                for (int ct = 0; ct < 4; ++ct)
                    acc[rt][ct] = __builtin_amdgcn_mfma_f32_16x16x32_bf16(
                        af[rt], bfr[ct], acc[rt][ct], 0, 0, 0);
        }
    }

    // epilogue
    const int l15 = lane & 15, l4 = lane >> 4;
    float bv[4];
#pragma unroll
    for (int ct = 0; ct < 4; ++ct)
        bv[ct] = (MODE != 1 && bias) ? bias[colbase + wc + ct * 16 + l15] : 0.f;
#pragma unroll
    for (int rt = 0; rt < 4; ++rt) {
#pragma unroll
        for (int rg = 0; rg < 4; ++rg) {
            int row = rowbase + wr + rt * 16 + l4 * 4 + rg;
            if (row >= M) continue;
            float sc = 1.f;
            if (MODE == 0 && rowscale) sc = rowscale[row];
#pragma unroll
            for (int ct = 0; ct < 4; ++ct) {
                int col = colbase + wc + ct * 16 + l15;
                float v = acc[rt][ct][rg] + bv[ct];
                if (MODE == 0) v = fast_tanh(v) * sc;
                if (MODE <= 1)
                    ((ushort*)out)[(size_t)row * Nn + col] = f2bf(v);
                else
                    ((float*)out)[(size_t)row * Nn + col] = v;
            }
        }
    }
}

// ---------- launch ----------
extern "C" void kernel_launch(void* const* d_in, const int* in_sizes, int n_in,
                              void* d_out, int out_size, void* d_ws, size_t ws_size,
                              hipStream_t stream) {
    (void)n_in; (void)out_size; (void)ws_size;
    const float* in_feat = (const float*)d_in[0];
    const int*   src     = (const int*)d_in[1];
    const int*   dstp    = (const int*)d_in[2];
    const float* Wc0 = (const float*)d_in[3];  const float* bc0 = (const float*)d_in[4];
    const float* Wc1 = (const float*)d_in[5];  const float* bc1 = (const float*)d_in[6];
    const float* Wc2 = (const float*)d_in[7];  const float* bc2 = (const float*)d_in[8];
    const float* Wr0 = (const float*)d_in[9];  const float* br0 = (const float*)d_in[10];
    const float* Wr1 = (const float*)d_in[11]; const float* br1 = (const float*)d_in[12];
    const float* Wr2 = (const float*)d_in[13]; const float* br2 = (const float*)d_in[14];

    const int N = in_sizes[0] / 128;
    const int E = in_sizes[1];
    const int numBuckets = (N + ((1 << BSHIFT) - 1)) >> BSHIFT; // 196 for N=100000

    char* ws = (char*)d_ws;
    size_t off = 0;
    auto alloc = [&](size_t bytes) -> char* {
        char* p = ws + off;
        off += (bytes + 255) & ~(size_t)255;
        return p;
    };
    char* S1 = alloc((size_t)N * 256 * 2);
    char* S2 = alloc((size_t)N * 256 * 2);   // pairs (E*8 <= 12.8MB) aliases S2 during CSR build
    int* csr    = (int*)alloc((size_t)E * 4);
    int* roff   = (int*)alloc((size_t)(N + 1) * 4);
    int* outc   = (int*)alloc((size_t)N * 4);
    float* sOut = (float*)alloc((size_t)N * 4);
    float* sIn  = (float*)alloc((size_t)N * 4);
    ushort* Wt  = (ushort*)alloc(262144 * 2);
    int* gbc        = (int*)alloc(256 * 4);
    int* bucketBase = (int*)alloc(257 * 4);
    int* pairCursor = (int*)alloc(256 * 4);
    uint2* pairs = (uint2*)S2;

    hipMemsetAsync(outc, 0, (size_t)N * 4, stream);
    hipMemsetAsync(gbc, 0, 256 * 4, stream);

    int nblk = (E + CHUNK - 1) / CHUNK;
    bucket_count<<<nblk, 256, 0, stream>>>(src, dstp, gbc, outc, E);
    scan_buckets<<<1, 256, 0, stream>>>(gbc, bucketBase, pairCursor, roff, N, E);
    part_scatter<<<nblk, 256, 0, stream>>>(src, dstp, pairCursor, pairs, E);
    build_bucket<<<numBuckets, 256, 0, stream>>>(pairs, bucketBase, roff, sIn, csr, N);

    convw<<<262144 / 256, 256, 0, stream>>>(Wc0, Wc1, Wc2, Wr0, Wr1, Wr2, Wt);

    ushort* Xs = (ushort*)S1;
    prescale<<<(N * 32 + 255) / 256, 256, 0, stream>>>(in_feat, outc, Xs, sOut, N * 32);

    int aggGrid = (N + 3) / 4;
    dim3 g2((N + 127) / 128, 2), g1((N + 127) / 128, 1);

    ushort* A0 = (ushort*)S2;
    agg128<<<aggGrid, 256, 0, stream>>>(Xs, csr, roff, sIn, A0, N);
    ushort* B1 = (ushort*)S1;
    gemm_kernel<0><<<g2, 256, 0, stream>>>(A0, Wt, bc0, sOut, B1, N, 128, 256);
    ushort* A1 = (ushort*)S2;
    agg256<<<aggGrid, 256, 0, stream>>>(B1, csr, roff, sIn, A1, N);
    ushort* B2 = (ushort*)S1;
    gemm_kernel<0><<<g2, 256, 0, stream>>>(A1, Wt + 32768, bc1, sOut, B2, N, 256, 256);
    ushort* T3 = (ushort*)S2;
    gemm_kernel<1><<<g1, 256, 0, stream>>>(B2, Wt + 98304, nullptr, nullptr, T3, N, 256, 128);
    float* outh = (float*)d_out;
    ushort* Hbf = (ushort*)S1;
    agg_softmax<<<aggGrid, 256, 0, stream>>>(T3, csr, roff, sIn, bc2, outh, Hbf, N);
    ushort* R1 = (ushort*)S2;
    gemm_kernel<0><<<g2, 256, 0, stream>>>(Hbf, Wt + 131072, br0, nullptr, R1, N, 128, 256);
    ushort* R2 = (ushort*)S1;
    gemm_kernel<0><<<g2, 256, 0, stream>>>(R1, Wt + 163840, br1, nullptr, R2, N, 256, 256);
    float* logits = (float*)S2;
    gemm_kernel<2><<<g1, 256, 0, stream>>>(R2, Wt + 229376, br2, nullptr, logits, N, 256, 128);
    softmax_r<<<aggGrid, 256, 0, stream>>>(logits, outh + (size_t)N * 128, N);
}